// Round 1
// baseline (457.052 us; speedup 1.0000x reference)
//
#include <hip/hip_runtime.h>
#include <hip/hip_bf16.h>
#include <math.h>

// Problem constants
#define BATCH 16384
#define DIN   480
#define DH    512
#define DOUT  360
#define NEXP  8
#define GIN   64
#define GH    128

typedef short bf16x8 __attribute__((ext_vector_type(8)));
typedef float f32x4  __attribute__((ext_vector_type(4)));

__device__ __forceinline__ short f2bf(float f) {
    __hip_bfloat16 h = __float2bfloat16(f);
    return *reinterpret_cast<short*>(&h);
}
__device__ __forceinline__ float eluf(float x) { return x > 0.f ? x : expf(x) - 1.f; }

// ---------------------------------------------------------------------------
// Kernel 1: xn = (x - mu) / sigma, store bf16.  grid = BATCH blocks x 256.
// ---------------------------------------------------------------------------
__global__ void prep_xn_kernel(const float* __restrict__ x,
                               const float* __restrict__ Xnorm,
                               short* __restrict__ xnbf) {
    const int row = blockIdx.x;
    const size_t base = (size_t)row * DIN;
    for (int i = threadIdx.x; i < DIN; i += 256) {
        float v = (x[base + i] - Xnorm[i]) / Xnorm[DIN + i];
        xnbf[base + i] = f2bf(v);
    }
}

// ---------------------------------------------------------------------------
// Kernel 2: transpose + convert W (E,K,N) f32 -> Wt (E,NPAD,K) bf16, zero pad.
// 32x32 tiles, block 256. grid = E * (K/32) * (NPAD/32)
// ---------------------------------------------------------------------------
__global__ void transpose_w_kernel(const float* __restrict__ src,
                                   short* __restrict__ dst,
                                   int K, int N, int NPAD) {
    __shared__ float tile[32][33];
    const int ntn = NPAD / 32;
    const int ntk = K / 32;
    int lin = blockIdx.x;
    const int e  = lin / (ntk * ntn);
    lin -= e * ntk * ntn;
    const int kt = lin / ntn;
    const int nt = lin % ntn;
    const int t = threadIdx.x;
    #pragma unroll
    for (int r = 0; r < 4; ++r) {
        int idx = t + r * 256;
        int i = idx >> 5;          // k within tile
        int j = idx & 31;          // n within tile
        int k = kt * 32 + i;
        int n = nt * 32 + j;
        float v = (n < N) ? src[((size_t)e * K + k) * N + n] : 0.f;
        tile[i][j] = v;
    }
    __syncthreads();
    #pragma unroll
    for (int r = 0; r < 4; ++r) {
        int idx = t + r * 256;
        int i2 = idx & 31;         // k (contiguous on write)
        int j2 = idx >> 5;         // n
        dst[((size_t)e * NPAD + nt * 32 + j2) * K + kt * 32 + i2] = f2bf(tile[i2][j2]);
    }
}

// ---------------------------------------------------------------------------
// Kernel 3: gating MLP -> softmax weights w[B][8] (fp32).
// grid 256 blocks x 256 thr (4 waves). Each wave: 16 rows sequentially.
// G2 (64KB) + G3 staged in LDS; G1 (32KB) from global (L1-resident).
// ---------------------------------------------------------------------------
__global__ __launch_bounds__(256) void gating_kernel(
    const float* __restrict__ x, const float* __restrict__ Xnorm,
    const float* __restrict__ G1W, const float* __restrict__ G1b,
    const float* __restrict__ G2W, const float* __restrict__ G2b,
    const float* __restrict__ G3W, const float* __restrict__ G3b,
    const int* __restrict__ gidx, float* __restrict__ wout) {

    __shared__ float g2s[GH * GH];      // 64 KB
    __shared__ float g3s[GH * NEXP];    // 4 KB
    __shared__ float b1s[GH], b2s[GH], b3s[NEXP];
    __shared__ float g0b[4][GIN], h1b[4][GH], h2b[4][GH];

    const int t = threadIdx.x;
    const int lane = t & 63;
    const int wid  = t >> 6;

    for (int i = t; i < GH * GH; i += 256) g2s[i] = G2W[i];
    for (int i = t; i < GH * NEXP; i += 256) g3s[i] = G3W[i];
    if (t < GH) { b1s[t] = G1b[t]; b2s[t] = G2b[t]; }
    if (t < NEXP) b3s[t] = G3b[t];
    __syncthreads();

    const int gi = gidx[lane];
    const float mu = Xnorm[gi];
    const float inv_sig = 1.f / Xnorm[DIN + gi];

    for (int it = 0; it < 16; ++it) {
        const int row = (blockIdx.x * 4 + wid) * 16 + it;
        float g0 = (x[(size_t)row * DIN + gi] - mu) * inv_sig;
        g0b[wid][lane] = g0;
        __syncthreads();
        // layer 1: 64 -> 128
        float h1a = b1s[lane], h1c = b1s[lane + 64];
        #pragma unroll 8
        for (int i = 0; i < GIN; ++i) {
            float g = g0b[wid][i];
            h1a += g * G1W[i * GH + lane];
            h1c += g * G1W[i * GH + lane + 64];
        }
        h1b[wid][lane] = eluf(h1a);
        h1b[wid][lane + 64] = eluf(h1c);
        __syncthreads();
        // layer 2: 128 -> 128
        float h2a = b2s[lane], h2c = b2s[lane + 64];
        #pragma unroll 8
        for (int i = 0; i < GH; ++i) {
            float h = h1b[wid][i];
            h2a += h * g2s[i * GH + lane];
            h2c += h * g2s[i * GH + lane + 64];
        }
        h2b[wid][lane] = eluf(h2a);
        h2b[wid][lane + 64] = eluf(h2c);
        __syncthreads();
        // layer 3: 128 -> 8 logits; lane = chunk*8 + e pattern
        const int e  = lane & 7;
        const int ch = lane >> 3;
        float p = 0.f;
        #pragma unroll
        for (int i2 = 0; i2 < 16; ++i2) {
            int i = ch * 16 + i2;
            p += h2b[wid][i] * g3s[i * NEXP + e];
        }
        p += __shfl_xor(p, 8);
        p += __shfl_xor(p, 16);
        p += __shfl_xor(p, 32);
        p += b3s[e];
        float mx = p;
        mx = fmaxf(mx, __shfl_xor(mx, 1));
        mx = fmaxf(mx, __shfl_xor(mx, 2));
        mx = fmaxf(mx, __shfl_xor(mx, 4));
        float ex = expf(p - mx);
        float sm = ex;
        sm += __shfl_xor(sm, 1);
        sm += __shfl_xor(sm, 2);
        sm += __shfl_xor(sm, 4);
        float wv = ex / sm;
        if (lane < NEXP) wout[(size_t)row * NEXP + lane] = wv;
        __syncthreads();
    }
}

// ---------------------------------------------------------------------------
// Kernel 4: expert layer.  out[b,n] = act( sum_e w[b,e] * (A[b,:]@W_e[:,n] + bias_e[n]) )
// BM=128, BN=128, BK=64; 4 waves (2x2), 16x16x32 bf16 MFMA, 4x4 frags/wave.
// A: bf16 [B][APITCH]; Wt: bf16 [E][NPAD][KEXP] (transposed, K-contiguous).
// MODE 0: ELU -> bf16 out (pitch NPAD).  MODE 1: *Ys+Yb -> f32 out (pitch NREAL).
// ---------------------------------------------------------------------------
template<int KEXP, int APITCH, int NPAD, int NREAL, int MODE>
__global__ __launch_bounds__(256, 2) void expert_layer_kernel(
    const short* __restrict__ A, const short* __restrict__ Wt,
    const float* __restrict__ wgate, const float* __restrict__ bias,
    const float* __restrict__ Ynorm, void* __restrict__ Out) {

    constexpr int LDP = 72;   // padded LDS pitch (elems): stride 144B -> 2-way conflicts only
    __shared__ __align__(16) short As[128 * LDP];
    __shared__ __align__(16) short Bs[128 * LDP];
    __shared__ float wls[128 * NEXP];

    const int t = threadIdx.x;
    const int lane = t & 63;
    const int wid  = t >> 6;
    const int wr = wid >> 1, wc = wid & 1;
    const int l4 = lane >> 4, lr = lane & 15;
    const int m0 = blockIdx.y * 128;
    const int n0 = blockIdx.x * 128;

    // stage gating weights for this row block: 128x8 f32 = 256 float4
    {
        const float4* src = (const float4*)(wgate + (size_t)m0 * NEXP);
        ((float4*)wls)[t] = src[t];
    }

    f32x4 accF[4][4];
    #pragma unroll
    for (int mi = 0; mi < 4; ++mi)
        #pragma unroll
        for (int ni = 0; ni < 4; ++ni)
            accF[mi][ni] = (f32x4){0.f, 0.f, 0.f, 0.f};

    constexpr int KSTEPS = (KEXP + 63) / 64;

    for (int e = 0; e < NEXP; ++e) {
        f32x4 acc[4][4];
        #pragma unroll
        for (int mi = 0; mi < 4; ++mi)
            #pragma unroll
            for (int ni = 0; ni < 4; ++ni)
                acc[mi][ni] = (f32x4){0.f, 0.f, 0.f, 0.f};

        for (int kt = 0; kt < KSTEPS; ++kt) {
            __syncthreads();   // protect LDS from previous iteration's readers
            // stage A and B tiles: 128 rows x 64 cols bf16 each (8x 16B chunks/row)
            #pragma unroll
            for (int i = 0; i < 4; ++i) {
                int c = t + i * 256;
                int row = c >> 3;
                int col8 = (c & 7) * 8;
                int kg = kt * 64 + col8;
                uint4 va = {0u, 0u, 0u, 0u}, vb = {0u, 0u, 0u, 0u};
                if (kg < KEXP) {
                    va = *(const uint4*)(A + (size_t)(m0 + row) * APITCH + kg);
                    vb = *(const uint4*)(Wt + ((size_t)(e * NPAD + n0 + row)) * KEXP + kg);
                }
                *(uint4*)&As[row * LDP + col8] = va;
                *(uint4*)&Bs[row * LDP + col8] = vb;
            }
            __syncthreads();
            #pragma unroll
            for (int kk = 0; kk < 2; ++kk) {
                const int colb = kk * 32 + l4 * 8;
                bf16x8 a[4], b[4];
                #pragma unroll
                for (int mi = 0; mi < 4; ++mi)
                    a[mi] = *(const bf16x8*)&As[(wr * 64 + mi * 16 + lr) * LDP + colb];
                #pragma unroll
                for (int ni = 0; ni < 4; ++ni)
                    b[ni] = *(const bf16x8*)&Bs[(wc * 64 + ni * 16 + lr) * LDP + colb];
                #pragma unroll
                for (int mi = 0; mi < 4; ++mi)
                    #pragma unroll
                    for (int ni = 0; ni < 4; ++ni)
                        acc[mi][ni] = __builtin_amdgcn_mfma_f32_16x16x32_bf16(
                            a[mi], b[ni], acc[mi][ni], 0, 0, 0);
            }
        }

        // mix: accF += w_e[row] * (acc + bias_e[col])
        #pragma unroll
        for (int mi = 0; mi < 4; ++mi) {
            float wv[4];
            #pragma unroll
            for (int j = 0; j < 4; ++j)
                wv[j] = wls[(wr * 64 + mi * 16 + l4 * 4 + j) * NEXP + e];
            #pragma unroll
            for (int ni = 0; ni < 4; ++ni) {
                int ng = n0 + wc * 64 + ni * 16 + lr;
                float bv = (ng < NREAL) ? bias[(size_t)e * NREAL + ng] : 0.f;
                #pragma unroll
                for (int j = 0; j < 4; ++j)
                    accF[mi][ni][j] += wv[j] * (acc[mi][ni][j] + bv);
            }
        }
    }

    // epilogue
    #pragma unroll
    for (int mi = 0; mi < 4; ++mi) {
        #pragma unroll
        for (int j = 0; j < 4; ++j) {
            size_t rg = (size_t)(m0 + wr * 64 + mi * 16 + l4 * 4 + j);
            #pragma unroll
            for (int ni = 0; ni < 4; ++ni) {
                int ng = n0 + wc * 64 + ni * 16 + lr;
                float v = accF[mi][ni][j];
                if (MODE == 0) {
                    v = v > 0.f ? v : expf(v) - 1.f;
                    ((short*)Out)[rg * NPAD + ng] = f2bf(v);
                } else {
                    if (ng < NREAL) {
                        ((float*)Out)[rg * NREAL + ng] = v * Ynorm[NREAL + ng] + Ynorm[ng];
                    }
                }
            }
        }
    }
}

// ---------------------------------------------------------------------------
extern "C" void kernel_launch(void* const* d_in, const int* in_sizes, int n_in,
                              void* d_out, int out_size, void* d_ws, size_t ws_size,
                              hipStream_t stream) {
    const float* x     = (const float*)d_in[0];
    const float* Xnorm = (const float*)d_in[1];
    const float* Ynorm = (const float*)d_in[2];
    const float* G1W   = (const float*)d_in[3];
    const float* G1b   = (const float*)d_in[4];
    const float* G2W   = (const float*)d_in[5];
    const float* G2b   = (const float*)d_in[6];
    const float* G3W   = (const float*)d_in[7];
    const float* G3b   = (const float*)d_in[8];
    const float* W1    = (const float*)d_in[9];
    const float* b1    = (const float*)d_in[10];
    const float* W2    = (const float*)d_in[11];
    const float* b2    = (const float*)d_in[12];
    const float* W3    = (const float*)d_in[13];
    const float* b3    = (const float*)d_in[14];
    const int*   gidx  = (const int*)d_in[15];

    // workspace layout
    char* ws = (char*)d_ws;
    size_t off = 0;
    short* xnbf = (short*)(ws + off); off += (size_t)BATCH * DIN * 2;        // 15.7 MB
    short* m1   = (short*)(ws + off); off += (size_t)BATCH * DH * 2;         // 16.8 MB
    short* m2   = (short*)(ws + off); off += (size_t)BATCH * DH * 2;         // 16.8 MB
    short* Wt1  = (short*)(ws + off); off += (size_t)NEXP * DH * DIN * 2;    // 3.9 MB
    short* Wt2  = (short*)(ws + off); off += (size_t)NEXP * DH * DH * 2;     // 4.2 MB
    short* Wt3  = (short*)(ws + off); off += (size_t)NEXP * 384 * DH * 2;    // 3.1 MB
    float* wg   = (float*)(ws + off); off += (size_t)BATCH * NEXP * 4;       // 0.5 MB
    if (off > ws_size) return;  // workspace too small; bail

    // 1. normalize x -> bf16
    prep_xn_kernel<<<BATCH, 256, 0, stream>>>(x, Xnorm, xnbf);

    // 2. transpose weights to [E][NPAD][K] bf16
    transpose_w_kernel<<<NEXP * (DIN / 32) * (DH / 32), 256, 0, stream>>>(W1, Wt1, DIN, DH, DH);
    transpose_w_kernel<<<NEXP * (DH / 32) * (DH / 32), 256, 0, stream>>>(W2, Wt2, DH, DH, DH);
    transpose_w_kernel<<<NEXP * (DH / 32) * (384 / 32), 256, 0, stream>>>(W3, Wt3, DH, DOUT, 384);

    // 3. gating -> w[B][8]
    gating_kernel<<<256, 256, 0, stream>>>(x, Xnorm, G1W, G1b, G2W, G2b, G3W, G3b, gidx, wg);

    // 4. expert layers
    expert_layer_kernel<DIN, DIN, DH, DH, 0>
        <<<dim3(DH / 128, BATCH / 128), 256, 0, stream>>>(xnbf, Wt1, wg, b1, Ynorm, m1);
    expert_layer_kernel<DH, DH, DH, DH, 0>
        <<<dim3(DH / 128, BATCH / 128), 256, 0, stream>>>(m1, Wt2, wg, b2, Ynorm, m2);
    expert_layer_kernel<DH, DH, 384, DOUT, 1>
        <<<dim3(384 / 128, BATCH / 128), 256, 0, stream>>>(m2, Wt3, wg, b3, Ynorm, (void*)d_out);
}

// Round 2
// 335.328 us; speedup vs baseline: 1.3630x; 1.3630x over previous
//
#include <hip/hip_runtime.h>
#include <hip/hip_bf16.h>
#include <math.h>

// Problem constants
#define BATCH 16384
#define DIN   480
#define DH    512
#define DOUT  360
#define NEXP  8
#define GIN   64
#define GH    128
#define KP    512          // padded K for all expert layers

typedef short bf16x8 __attribute__((ext_vector_type(8)));
typedef float f32x4  __attribute__((ext_vector_type(4)));

__device__ __forceinline__ short f2bf(float f) {
    __hip_bfloat16 h = __float2bfloat16(f);
    return *reinterpret_cast<short*>(&h);
}
__device__ __forceinline__ float eluf(float x) { return x > 0.f ? x : expf(x) - 1.f; }

__device__ __forceinline__ void gll16(const void* g, void* l) {
    __builtin_amdgcn_global_load_lds(
        (const __attribute__((address_space(1))) unsigned int*)g,
        (__attribute__((address_space(3))) unsigned int*)l, 16, 0, 0);
}

// ---------------------------------------------------------------------------
// Kernel 1: xn = (x - mu) / sigma -> bf16, pitch 512 (cols 480..511 zero).
// grid = BATCH*64/256 blocks; each thread does 8 cols.
// ---------------------------------------------------------------------------
__global__ void prep_xn_kernel(const float* __restrict__ x,
                               const float* __restrict__ Xnorm,
                               short* __restrict__ xnbf) {
    const int tid = blockIdx.x * 256 + threadIdx.x;
    const int row = tid >> 6;
    const int c   = (tid & 63) * 8;
    short v8[8];
    if (c < DIN) {
        #pragma unroll
        for (int j = 0; j < 8; ++j) {
            float v = (x[(size_t)row * DIN + c + j] - Xnorm[c + j]) / Xnorm[DIN + c + j];
            v8[j] = f2bf(v);
        }
    } else {
        #pragma unroll
        for (int j = 0; j < 8; ++j) v8[j] = 0;
    }
    *(uint4*)&xnbf[(size_t)row * KP + c] = *(uint4*)v8;
}

// ---------------------------------------------------------------------------
// Kernel 2: transpose + convert W (E,K,N) f32 -> Wt (E,NPAD,KP) bf16, zero pad.
// ---------------------------------------------------------------------------
__global__ void transpose_w_kernel(const float* __restrict__ src,
                                   short* __restrict__ dst,
                                   int K, int N, int NPAD) {
    __shared__ float tile[32][33];
    const int ntn = NPAD / 32;
    const int ntk = KP / 32;
    int lin = blockIdx.x;
    const int e  = lin / (ntk * ntn);
    lin -= e * ntk * ntn;
    const int kt = lin / ntn;
    const int nt = lin % ntn;
    const int t = threadIdx.x;
    #pragma unroll
    for (int r = 0; r < 4; ++r) {
        int idx = t + r * 256;
        int i = idx >> 5;          // k within tile
        int j = idx & 31;          // n within tile
        int k = kt * 32 + i;
        int n = nt * 32 + j;
        float v = (n < N && k < K) ? src[((size_t)e * K + k) * N + n] : 0.f;
        tile[i][j] = v;
    }
    __syncthreads();
    #pragma unroll
    for (int r = 0; r < 4; ++r) {
        int idx = t + r * 256;
        int i2 = idx & 31;         // k (contiguous on write)
        int j2 = idx >> 5;         // n
        dst[((size_t)e * NPAD + nt * 32 + j2) * KP + kt * 32 + i2] = f2bf(tile[i2][j2]);
    }
}

// ---------------------------------------------------------------------------
// Kernel 3: gating MLP -> softmax weights w[B][8] (fp32).  (unchanged, passing)
// ---------------------------------------------------------------------------
__global__ __launch_bounds__(256) void gating_kernel(
    const float* __restrict__ x, const float* __restrict__ Xnorm,
    const float* __restrict__ G1W, const float* __restrict__ G1b,
    const float* __restrict__ G2W, const float* __restrict__ G2b,
    const float* __restrict__ G3W, const float* __restrict__ G3b,
    const int* __restrict__ gidx, float* __restrict__ wout) {

    __shared__ float g2s[GH * GH];
    __shared__ float g3s[GH * NEXP];
    __shared__ float b1s[GH], b2s[GH], b3s[NEXP];
    __shared__ float g0b[4][GIN], h1b[4][GH], h2b[4][GH];

    const int t = threadIdx.x;
    const int lane = t & 63;
    const int wid  = t >> 6;

    for (int i = t; i < GH * GH; i += 256) g2s[i] = G2W[i];
    for (int i = t; i < GH * NEXP; i += 256) g3s[i] = G3W[i];
    if (t < GH) { b1s[t] = G1b[t]; b2s[t] = G2b[t]; }
    if (t < NEXP) b3s[t] = G3b[t];
    __syncthreads();

    const int gi = gidx[lane];
    const float mu = Xnorm[gi];
    const float inv_sig = 1.f / Xnorm[DIN + gi];

    for (int it = 0; it < 16; ++it) {
        const int row = (blockIdx.x * 4 + wid) * 16 + it;
        float g0 = (x[(size_t)row * DIN + gi] - mu) * inv_sig;
        g0b[wid][lane] = g0;
        __syncthreads();
        float h1a = b1s[lane], h1c = b1s[lane + 64];
        #pragma unroll 8
        for (int i = 0; i < GIN; ++i) {
            float g = g0b[wid][i];
            h1a += g * G1W[i * GH + lane];
            h1c += g * G1W[i * GH + lane + 64];
        }
        h1b[wid][lane] = eluf(h1a);
        h1b[wid][lane + 64] = eluf(h1c);
        __syncthreads();
        float h2a = b2s[lane], h2c = b2s[lane + 64];
        #pragma unroll 8
        for (int i = 0; i < GH; ++i) {
            float h = h1b[wid][i];
            h2a += h * g2s[i * GH + lane];
            h2c += h * g2s[i * GH + lane + 64];
        }
        h2b[wid][lane] = eluf(h2a);
        h2b[wid][lane + 64] = eluf(h2c);
        __syncthreads();
        const int e  = lane & 7;
        const int ch = lane >> 3;
        float p = 0.f;
        #pragma unroll
        for (int i2 = 0; i2 < 16; ++i2) {
            int i = ch * 16 + i2;
            p += h2b[wid][i] * g3s[i * NEXP + e];
        }
        p += __shfl_xor(p, 8);
        p += __shfl_xor(p, 16);
        p += __shfl_xor(p, 32);
        p += b3s[e];
        float mx = p;
        mx = fmaxf(mx, __shfl_xor(mx, 1));
        mx = fmaxf(mx, __shfl_xor(mx, 2));
        mx = fmaxf(mx, __shfl_xor(mx, 4));
        float ex = expf(p - mx);
        float sm = ex;
        sm += __shfl_xor(sm, 1);
        sm += __shfl_xor(sm, 2);
        sm += __shfl_xor(sm, 4);
        float wv = ex / sm;
        if (lane < NEXP) wout[(size_t)row * NEXP + lane] = wv;
        __syncthreads();
    }
}

// ---------------------------------------------------------------------------
// Kernel 4 v2: expert layer.  out[b,n] = act( sum_e w[b,e]*(A@W_e)[b,n] + sum_e w[b,e]*b_e[n] )
// BM=128, BN=128, BK=64, K=KP=512 fixed; 4 waves (2x2), 16x16x32 bf16 MFMA.
// global_load_lds(16B) staging, double-buffered LDS, stage-before-compute.
// XOR slot-swizzle (slot ^= row&7) applied on the GLOBAL source and on ds_read.
// A: bf16 [B][KP]; Wt: bf16 [E][NPAD][KP].
// ---------------------------------------------------------------------------
template<int NPAD, int NREAL, int MODE>
__global__ __launch_bounds__(256, 2) void expert_v2_kernel(
    const short* __restrict__ A, const short* __restrict__ Wt,
    const float* __restrict__ wgate, const float* __restrict__ bias,
    const float* __restrict__ Ynorm, void* __restrict__ Out) {

    __shared__ __align__(16) short lds[2][2][128 * 64];   // [buf][A/B][row*64+col]
    __shared__ float wlsT[NEXP][128];                     // gating weights, [e][row]

    const int t = threadIdx.x;
    const int lane = t & 63;
    const int wid  = t >> 6;
    const int wr = wid >> 1, wc = wid & 1;
    const int l4 = lane >> 4, lr = lane & 15;

    // XCD-chunked block swizzle (grid % 8 == 0)
    constexpr int NN = NPAD / 128;
    const int nwg = 128 * NN;
    const int cpx = nwg >> 3;
    const int lb  = (blockIdx.x & 7) * cpx + (blockIdx.x >> 3);
    const int m0  = (lb / NN) * 128;
    const int n0  = (lb % NN) * 128;

    // stage gating weights transposed: wlsT[e][row] = wgate[(m0+row)*8+e]
    for (int i = t; i < NEXP * 128; i += 256) {
        int e = i >> 7, r = i & 127;
        wlsT[e][r] = wgate[(size_t)(m0 + r) * NEXP + e];
    }

    // staging geometry: wave handles chunks q = wid*4+i (rows q*8..q*8+7)
    const int srow  = lane >> 3;              // 0..7
    const int sslot = (lane & 7) ^ srow;      // pre-swizzled source 16B-slot

    const short* baseA[4];
    const short* baseB[4];
    short* ldsA[2][4];
    short* ldsB[2][4];
    #pragma unroll
    for (int i = 0; i < 4; ++i) {
        int q = wid * 4 + i;
        baseA[i] = A  + (size_t)(m0 + q * 8 + srow) * KP + sslot * 8;
        baseB[i] = Wt + (size_t)(n0 + q * 8 + srow) * KP + sslot * 8;
        #pragma unroll
        for (int d = 0; d < 2; ++d) {
            ldsA[d][i] = &lds[d][0][q * 512];
            ldsB[d][i] = &lds[d][1][q * 512];
        }
    }

    f32x4 acc[4][4], accF[4][4];
    #pragma unroll
    for (int mi = 0; mi < 4; ++mi)
        #pragma unroll
        for (int ni = 0; ni < 4; ++ni) {
            acc[mi][ni]  = (f32x4){0.f, 0.f, 0.f, 0.f};
            accF[mi][ni] = (f32x4){0.f, 0.f, 0.f, 0.f};
        }

    // prologue: stage step 0 into buf 0
    #pragma unroll
    for (int i = 0; i < 4; ++i) {
        gll16(baseA[i], ldsA[0][i]);
        gll16(baseB[i], ldsB[0][i]);
    }
    __syncthreads();

    int cur = 0;
    for (int s = 0; s < 8 * NEXP; ++s) {
        // stage next step into the other buffer (overlaps with MFMA below)
        if (s < 8 * NEXP - 1) {
            const int sn  = s + 1;
            const int en  = sn >> 3;
            const int ktn = sn & 7;
            const size_t boff = (size_t)en * NPAD * KP + ktn * 64;
            const size_t aoff = (size_t)ktn * 64;
            #pragma unroll
            for (int i = 0; i < 4; ++i) {
                gll16(baseA[i] + aoff, ldsA[cur ^ 1][i]);
                gll16(baseB[i] + boff, ldsB[cur ^ 1][i]);
            }
        }

        // compute on current buffer
        {
            const short* Ab = &lds[cur][0][0];
            const short* Bb = &lds[cur][1][0];
            #pragma unroll
            for (int kk = 0; kk < 2; ++kk) {
                const int xo = (kk * 32 + l4 * 8) ^ ((lr & 7) << 3);
                bf16x8 a[4], b[4];
                #pragma unroll
                for (int mi = 0; mi < 4; ++mi)
                    a[mi] = *(const bf16x8*)(Ab + (wr * 64 + mi * 16 + lr) * 64 + xo);
                #pragma unroll
                for (int ni = 0; ni < 4; ++ni)
                    b[ni] = *(const bf16x8*)(Bb + (wc * 64 + ni * 16 + lr) * 64 + xo);
                #pragma unroll
                for (int mi = 0; mi < 4; ++mi)
                    #pragma unroll
                    for (int ni = 0; ni < 4; ++ni)
                        acc[mi][ni] = __builtin_amdgcn_mfma_f32_16x16x32_bf16(
                            a[mi], b[ni], acc[mi][ni], 0, 0, 0);
            }
        }

        // expert boundary: accF += w_e * acc; reset acc
        if ((s & 7) == 7) {
            const int e = s >> 3;
            #pragma unroll
            for (int mi = 0; mi < 4; ++mi) {
                f32x4 wv = *(const f32x4*)&wlsT[e][wr * 64 + mi * 16 + l4 * 4];
                #pragma unroll
                for (int ni = 0; ni < 4; ++ni) {
                    #pragma unroll
                    for (int j = 0; j < 4; ++j)
                        accF[mi][ni][j] += wv[j] * acc[mi][ni][j];
                    acc[mi][ni] = (f32x4){0.f, 0.f, 0.f, 0.f};
                }
            }
        }

        __syncthreads();
        cur ^= 1;
    }

    // epilogue: rank-1 bias term  accF += sum_e w_e[row] * bias_e[col]
    {
        float bv[4][NEXP];
        #pragma unroll
        for (int ni = 0; ni < 4; ++ni) {
            int ng = n0 + wc * 64 + ni * 16 + lr;
            #pragma unroll
            for (int e = 0; e < NEXP; ++e)
                bv[ni][e] = (ng < NREAL) ? bias[(size_t)e * NREAL + ng] : 0.f;
        }
        #pragma unroll
        for (int mi = 0; mi < 4; ++mi) {
            f32x4 wv[NEXP];
            #pragma unroll
            for (int e = 0; e < NEXP; ++e)
                wv[e] = *(const f32x4*)&wlsT[e][wr * 64 + mi * 16 + l4 * 4];
            #pragma unroll
            for (int ni = 0; ni < 4; ++ni)
                #pragma unroll
                for (int j = 0; j < 4; ++j) {
                    float sum = 0.f;
                    #pragma unroll
                    for (int e = 0; e < NEXP; ++e) sum += wv[e][j] * bv[ni][e];
                    accF[mi][ni][j] += sum;
                }
        }
    }

    // store
    #pragma unroll
    for (int mi = 0; mi < 4; ++mi) {
        #pragma unroll
        for (int j = 0; j < 4; ++j) {
            size_t rg = (size_t)(m0 + wr * 64 + mi * 16 + l4 * 4 + j);
            #pragma unroll
            for (int ni = 0; ni < 4; ++ni) {
                int ng = n0 + wc * 64 + ni * 16 + lr;
                float v = accF[mi][ni][j];
                if (MODE == 0) {
                    v = v > 0.f ? v : expf(v) - 1.f;
                    ((short*)Out)[rg * NPAD + ng] = f2bf(v);
                } else {
                    if (ng < NREAL)
                        ((float*)Out)[rg * NREAL + ng] = v * Ynorm[NREAL + ng] + Ynorm[ng];
                }
            }
        }
    }
}

// ---------------------------------------------------------------------------
extern "C" void kernel_launch(void* const* d_in, const int* in_sizes, int n_in,
                              void* d_out, int out_size, void* d_ws, size_t ws_size,
                              hipStream_t stream) {
    const float* x     = (const float*)d_in[0];
    const float* Xnorm = (const float*)d_in[1];
    const float* Ynorm = (const float*)d_in[2];
    const float* G1W   = (const float*)d_in[3];
    const float* G1b   = (const float*)d_in[4];
    const float* G2W   = (const float*)d_in[5];
    const float* G2b   = (const float*)d_in[6];
    const float* G3W   = (const float*)d_in[7];
    const float* G3b   = (const float*)d_in[8];
    const float* W1    = (const float*)d_in[9];
    const float* b1    = (const float*)d_in[10];
    const float* W2    = (const float*)d_in[11];
    const float* b2    = (const float*)d_in[12];
    const float* W3    = (const float*)d_in[13];
    const float* b3    = (const float*)d_in[14];
    const int*   gidx  = (const int*)d_in[15];

    // workspace layout (m2 aliases xnbf: xnbf is fully consumed by layer 1)
    char* ws = (char*)d_ws;
    size_t off = 0;
    short* xnbf = (short*)(ws + off); off += (size_t)BATCH * KP * 2;        // 16.8 MB
    short* m1   = (short*)(ws + off); off += (size_t)BATCH * DH * 2;        // 16.8 MB
    short* Wt1  = (short*)(ws + off); off += (size_t)NEXP * DH  * KP * 2;   // 4.2 MB
    short* Wt2  = (short*)(ws + off); off += (size_t)NEXP * DH  * KP * 2;   // 4.2 MB
    short* Wt3  = (short*)(ws + off); off += (size_t)NEXP * 384 * KP * 2;   // 3.1 MB
    float* wg   = (float*)(ws + off); off += (size_t)BATCH * NEXP * 4;      // 0.5 MB
    short* m2   = xnbf;
    if (off > ws_size) return;

    // 1. normalize x -> bf16 (pitch 512, zero-padded)
    prep_xn_kernel<<<BATCH * 64 / 256, 256, 0, stream>>>(x, Xnorm, xnbf);

    // 2. transpose weights to [E][NPAD][KP] bf16 (K zero-padded)
    transpose_w_kernel<<<NEXP * (KP / 32) * (DH / 32), 256, 0, stream>>>(W1, Wt1, DIN, DH, DH);
    transpose_w_kernel<<<NEXP * (KP / 32) * (DH / 32), 256, 0, stream>>>(W2, Wt2, DH, DH, DH);
    transpose_w_kernel<<<NEXP * (KP / 32) * (384 / 32), 256, 0, stream>>>(W3, Wt3, DH, DOUT, 384);

    // 3. gating -> w[B][8]
    gating_kernel<<<256, 256, 0, stream>>>(x, Xnorm, G1W, G1b, G2W, G2b, G3W, G3b, gidx, wg);

    // 4. expert layers
    expert_v2_kernel<DH, DH, 0>
        <<<(BATCH / 128) * (DH / 128), 256, 0, stream>>>(xnbf, Wt1, wg, b1, Ynorm, m1);
    expert_v2_kernel<DH, DH, 0>
        <<<(BATCH / 128) * (DH / 128), 256, 0, stream>>>(m1, Wt2, wg, b2, Ynorm, m2);
    expert_v2_kernel<384, DOUT, 1>
        <<<(BATCH / 128) * (384 / 128), 256, 0, stream>>>(m2, Wt3, wg, b3, Ynorm, (void*)d_out);
}